// Round 14
// baseline (127.266 us; speedup 1.0000x reference)
//
#include <hip/hip_runtime.h>

// GraphAttentionLayer: B=2, N=512, D=256, H=4, HD=64, slope=0.2
// Inputs f32, outputs f32 = concat(h_prime [B,N,256], e [B,N,N,4]).
// lrelu(x) = 0.6x + 0.4|x|; hk-dot term is j-constant -> cancels in softmax:
// score = 0.6*sum_f hq*a + 0.4*sum_f |hq+hk|*a.
// R14: i-tile 8 (block = b, 8 i-rows, one h; grid 512). Affordable now that
// hk lives in SGPRs (uniform scalar loads) and q-loads are coalesced f-major
// scalars (R13 transpose) — R9's spill cause is gone. Halves q/hv load
// instructions and hqT/hv L2 traffic at invariant VALU math.

#define NB 2
#define NN 512
#define DD 256
#define NH 4
#define HDIM 64

typedef __attribute__((ext_vector_type(2))) float f32x2;

__device__ __forceinline__ f32x2 pk_fma(f32x2 a, f32x2 b, f32x2 c) {
    return __builtin_elementwise_fma(a, b, c);
}
__device__ __forceinline__ f32x2 pk_abs(f32x2 t) {
    return __builtin_elementwise_max(t, -t);     // v_pk_max_f32 with neg mod
}

// ---------------- proj: register-blocked GEMM, 16 rows x 128 cols/block ----
// m==0 (query) writes transposed: hqT[((b*NH+h)*HDIM+f)*NN + j].
__global__ __launch_bounds__(256, 4) void proj_kernel(
    const float* __restrict__ q, const float* __restrict__ kin, const float* __restrict__ vin,
    const float* __restrict__ wq, const float* __restrict__ bq,
    const float* __restrict__ wv, const float* __restrict__ bv,
    float* __restrict__ hqt, float* __restrict__ hk, float* __restrict__ hv)
{
    const int m = blockIdx.z;
    const float* x    = (m == 0) ? q  : (m == 1) ? kin : vin;
    const float* w    = (m == 2) ? wv : wq;
    const float* bias = (m == 2) ? bv : bq;
    float* out        = (m == 0) ? hqt : (m == 1) ? hk : hv;

    const int r0 = blockIdx.x * 16;
    const int cb = blockIdx.y * 128;
    const int t  = threadIdx.x;

    __shared__ float xs[16][DD + 4];

    #pragma unroll
    for (int p = 0; p < 4; ++p) {
        const int idx = t + 256 * p;
        const int row = idx >> 6;
        const int kc  = idx & 63;
        const float4 v = *reinterpret_cast<const float4*>(&x[(size_t)(r0 + row) * DD + kc * 4]);
        *reinterpret_cast<float4*>(&xs[row][kc * 4]) = v;
    }
    __syncthreads();

    const int row0 = (t >> 5) * 2;
    const int c0   = (t & 31) * 4;

    const float4 b4 = *reinterpret_cast<const float4*>(&bias[cb + c0]);
    float acc[2][4];
    #pragma unroll
    for (int r = 0; r < 2; ++r) { acc[r][0]=b4.x; acc[r][1]=b4.y; acc[r][2]=b4.z; acc[r][3]=b4.w; }

    for (int kt = 0; kt < DD; kt += 4) {
        const float4 a0 = *reinterpret_cast<const float4*>(&xs[row0][kt]);
        const float4 a1 = *reinterpret_cast<const float4*>(&xs[row0 + 1][kt]);
        const float xa0[4] = {a0.x, a0.y, a0.z, a0.w};
        const float xa1[4] = {a1.x, a1.y, a1.z, a1.w};
        #pragma unroll
        for (int kk = 0; kk < 4; ++kk) {
            const float4 w4 = *reinterpret_cast<const float4*>(&w[(size_t)(kt + kk) * DD + cb + c0]);
            const float wv4[4] = {w4.x, w4.y, w4.z, w4.w};
            #pragma unroll
            for (int c = 0; c < 4; ++c) {
                acc[0][c] = fmaf(xa0[kk], wv4[c], acc[0][c]);
                acc[1][c] = fmaf(xa1[kk], wv4[c], acc[1][c]);
            }
        }
    }
    if (m == 0) {                                 // transposed scatter store
        #pragma unroll
        for (int r = 0; r < 2; ++r) {
            const int rg = r0 + row0 + r;
            const int bb = rg >> 9, j = rg & 511;
            #pragma unroll
            for (int c = 0; c < 4; ++c) {
                const int col = cb + c0 + c;
                const int hh = col >> 6, f = col & 63;
                out[(((size_t)(bb * NH) + hh) * HDIM + f) * NN + j] = acc[r][c];
            }
        }
    } else {
        #pragma unroll
        for (int r = 0; r < 2; ++r) {
            float4 o; o.x = acc[r][0]; o.y = acc[r][1]; o.z = acc[r][2]; o.w = acc[r][3];
            *reinterpret_cast<float4*>(&out[(size_t)(r0 + row0 + r) * DD + cb + c0]) = o;
        }
    }
}

// ------ attn: block = (b, 8 i-rows, one head), 512 threads, 8 waves --------
__global__ __launch_bounds__(512, 8) void attn_kernel(
    const float* __restrict__ hqt, const float* __restrict__ hk, const float* __restrict__ hv,
    const float* __restrict__ a, float* __restrict__ out_hp, float* __restrict__ out_e)
{
    const int t    = threadIdx.x;
    // XCD swizzle: h-blocks of one (b,i-tile) are 128 apart (≡ mod 8 -> same XCD)
    const int h    = blockIdx.x >> 7;
    const int rest = blockIdx.x & 127;
    const int b    = rest >> 6;
    const int i0   = (rest & 63) * 8;

    __shared__ float s[8][NN + 8];                // [ii][j]  16.6 KB
    __shared__ float part[8][8][HDIM];            // [w][ii][col] 16 KB

    const float* hk0 = hk + ((size_t)(b * NN) + i0) * DD + h * HDIM;  // uniform

    // ---- Phase 1: thread = one j; f-major hqT -> lane-consecutive loads;
    // each q scalar serves 8 i-rows; hk via SGPR (uniform) loads.
    {
        const int j = t;
        const float* hqb = hqt + (size_t)(b * NH + h) * HDIM * NN;
        f32x2 accu = {0.f, 0.f};
        f32x2 acc[8] = {};
        #pragma unroll
        for (int fc = 0; fc < 16; ++fc) {
            const int fo = fc * 4;
            const float q0 = hqb[(size_t)(fo + 0) * NN + j];
            const float q1 = hqb[(size_t)(fo + 1) * NN + j];
            const float q2 = hqb[(size_t)(fo + 2) * NN + j];
            const float q3 = hqb[(size_t)(fo + 3) * NN + j];
            const float4 a4 = *reinterpret_cast<const float4*>(a + fo);        // uniform
            const f32x2 av[2] = {{a4.x, a4.y}, {a4.z, a4.w}};
            const f32x2 qv[2] = {{q0, q1}, {q2, q3}};
            #pragma unroll
            for (int ii = 0; ii < 8; ++ii) {
                const float4 kv = *reinterpret_cast<const float4*>(hk0 + ii * DD + fo); // uniform
                const f32x2 kk0 = {kv.x, kv.y}, kk1 = {kv.z, kv.w};
                acc[ii] = pk_fma(pk_abs(qv[0] + kk0), av[0], acc[ii]);
                acc[ii] = pk_fma(pk_abs(qv[1] + kk1), av[1], acc[ii]);
            }
            accu = pk_fma(qv[0], av[0], accu);
            accu = pk_fma(qv[1], av[1], accu);
        }
        const float su = 0.6f * (accu.x + accu.y);
        #pragma unroll
        for (int ii = 0; ii < 8; ++ii)
            s[ii][j] = fmaf(0.4f, acc[ii].x + acc[ii].y, su);
    }
    __syncthreads();

    // ---- Phase 2: softmax over j; 8 waves x 8 rows -> 1 row/wave.
    {
        const int wv = t >> 6, lane = t & 63;
        float* row = &s[wv][0];
        float vals[8]; float mx = -1e30f;
        #pragma unroll
        for (int k2 = 0; k2 < 8; ++k2) { vals[k2] = row[lane + 64 * k2]; mx = fmaxf(mx, vals[k2]); }
        #pragma unroll
        for (int off = 32; off; off >>= 1) mx = fmaxf(mx, __shfl_xor(mx, off, 64));
        float sum = 0.f;
        #pragma unroll
        for (int k2 = 0; k2 < 8; ++k2) { vals[k2] = __expf(vals[k2] - mx); sum += vals[k2]; }
        #pragma unroll
        for (int off = 32; off; off >>= 1) sum += __shfl_xor(sum, off, 64);
        const float inv = 1.0f / sum;
        #pragma unroll
        for (int k2 = 0; k2 < 8; ++k2) row[lane + 64 * k2] = vals[k2] * inv;
    }
    __syncthreads();

    // ---- e-write: out_e[b,i0+ii,j,h], stride-NH scalar stores (merge in L2
    // with the sibling h-blocks on the same XCD).
    {
        float* oe = out_e + (((size_t)(b * NN) + i0) * NN) * NH + h;
        #pragma unroll
        for (int k2 = 0; k2 < 8; ++k2) {
            const int idx = t + 512 * k2;         // 0..4095 = ii*512 + j
            const int ii = idx >> 9;
            const int j  = idx & 511;
            oe[((size_t)ii * NN + j) * NH] = s[ii][j];
        }
    }

    // ---- Phase 3: wave w owns j in [64w,64w+64); lane = (jsub, 4 cols).
    // Row-major float4 hv loads (each serves 8 i-rows); e via LDS broadcast;
    // jsub reduced in-wave via shfl_xor butterfly.
    {
        const int w    = t >> 6;
        const int lane = t & 63;
        const int jsub = lane >> 4;               // 0..3
        const int c0   = (lane & 15) * 4;         // col quad in h-slice
        const int jbase = w * 64;
        f32x2 acc0[8], acc1[8];
        #pragma unroll
        for (int ii = 0; ii < 8; ++ii) { acc0[ii] = f32x2{0.f, 0.f}; acc1[ii] = f32x2{0.f, 0.f}; }
        const float* hvb = hv + (size_t)(b * NN) * DD + h * HDIM + c0;
        #pragma unroll
        for (int it = 0; it < 16; ++it) {
            const int j = jbase + it * 4 + jsub;
            const float4 v4 = *reinterpret_cast<const float4*>(hvb + (size_t)j * DD);
            const f32x2 v0 = {v4.x, v4.y}, v1 = {v4.z, v4.w};
            #pragma unroll
            for (int ii = 0; ii < 8; ++ii) {
                const float e = s[ii][j];          // LDS broadcast (16 lanes/addr)
                const f32x2 e2 = {e, e};
                acc0[ii] = pk_fma(e2, v0, acc0[ii]);
                acc1[ii] = pk_fma(e2, v1, acc1[ii]);
            }
        }
        // reduce over jsub (lane bits 4,5) in-register
        #pragma unroll
        for (int ii = 0; ii < 8; ++ii) {
            #pragma unroll
            for (int off = 16; off <= 32; off <<= 1) {
                acc0[ii].x += __shfl_xor(acc0[ii].x, off, 64);
                acc0[ii].y += __shfl_xor(acc0[ii].y, off, 64);
                acc1[ii].x += __shfl_xor(acc1[ii].x, off, 64);
                acc1[ii].y += __shfl_xor(acc1[ii].y, off, 64);
            }
        }
        if (lane < 16) {
            #pragma unroll
            for (int ii = 0; ii < 8; ++ii) {
                float4 o; o.x = acc0[ii].x; o.y = acc0[ii].y; o.z = acc1[ii].x; o.w = acc1[ii].y;
                *reinterpret_cast<float4*>(&part[w][ii][c0]) = o;
            }
        }
    }
    __syncthreads();
    {
        const int ii = t >> 6, col = t & 63;      // 512 outputs
        float v = 0.f;
        #pragma unroll
        for (int w = 0; w < 8; ++w) v += part[w][ii][col];
        out_hp[((size_t)(b * NN) + i0 + ii) * DD + h * HDIM + col] = v > 0.f ? v : 0.f;
    }
}

extern "C" void kernel_launch(void* const* d_in, const int* in_sizes, int n_in,
                              void* d_out, int out_size, void* d_ws, size_t ws_size,
                              hipStream_t stream) {
    const float* q   = (const float*)d_in[0];
    const float* kin = (const float*)d_in[1];
    const float* vin = (const float*)d_in[2];
    const float* wq  = (const float*)d_in[3];
    const float* bq  = (const float*)d_in[4];
    const float* wv  = (const float*)d_in[5];
    const float* bv  = (const float*)d_in[6];
    const float* a   = (const float*)d_in[7];

    float* out_hp = (float*)d_out;                    // [B,N,256]
    float* out_e  = out_hp + (size_t)NB * NN * DD;    // [B,N,N,4]

    float* hqt = (float*)d_ws;                        // hqT[b][h][f][j], 1 MB
    float* hk  = hqt + (size_t)NB * NN * DD;
    float* hv  = hk  + (size_t)NB * NN * DD;

    proj_kernel<<<dim3(64, 2, 3), 256, 0, stream>>>(q, kin, vin, wq, bq, wv, bv, hqt, hk, hv);
    attn_kernel<<<dim3(NB * 64 * NH), 512, 0, stream>>>(hqt, hk, hv, a, out_hp, out_e);
}

// Round 15
// 107.289 us; speedup vs baseline: 1.1862x; 1.1862x over previous
//
#include <hip/hip_runtime.h>

// GraphAttentionLayer: B=2, N=512, D=256, H=4, HD=64, slope=0.2
// Inputs f32, outputs f32 = concat(h_prime [B,N,256], e [B,N,N,4]).
// lrelu(x) = 0.6x + 0.4|x|; hk-dot term is j-constant -> cancels in softmax:
// score = 0.6*sum_f hq*a + 0.4*sum_f |hq+hk|*a.
// R15: R14 (i-tile 8) with __launch_bounds__(512,4): R14's (512,8) capped
// VGPR at 64 -> accumulator arrays spilled to scratch (FETCH 21.5MB/WRITE
// 42MB of spill traffic, attn 67-76us). Cap 128 fits the ~90 live regs;
// 16 waves/CU is sufficient for this coalesced kernel (R10).

#define NB 2
#define NN 512
#define DD 256
#define NH 4
#define HDIM 64

typedef __attribute__((ext_vector_type(2))) float f32x2;

__device__ __forceinline__ f32x2 pk_fma(f32x2 a, f32x2 b, f32x2 c) {
    return __builtin_elementwise_fma(a, b, c);
}
__device__ __forceinline__ f32x2 pk_abs(f32x2 t) {
    return __builtin_elementwise_max(t, -t);     // v_pk_max_f32 with neg mod
}

// ---------------- proj: register-blocked GEMM, 16 rows x 128 cols/block ----
// m==0 (query) writes transposed: hqT[((b*NH+h)*HDIM+f)*NN + j].
__global__ __launch_bounds__(256, 4) void proj_kernel(
    const float* __restrict__ q, const float* __restrict__ kin, const float* __restrict__ vin,
    const float* __restrict__ wq, const float* __restrict__ bq,
    const float* __restrict__ wv, const float* __restrict__ bv,
    float* __restrict__ hqt, float* __restrict__ hk, float* __restrict__ hv)
{
    const int m = blockIdx.z;
    const float* x    = (m == 0) ? q  : (m == 1) ? kin : vin;
    const float* w    = (m == 2) ? wv : wq;
    const float* bias = (m == 2) ? bv : bq;
    float* out        = (m == 0) ? hqt : (m == 1) ? hk : hv;

    const int r0 = blockIdx.x * 16;
    const int cb = blockIdx.y * 128;
    const int t  = threadIdx.x;

    __shared__ float xs[16][DD + 4];

    #pragma unroll
    for (int p = 0; p < 4; ++p) {
        const int idx = t + 256 * p;
        const int row = idx >> 6;
        const int kc  = idx & 63;
        const float4 v = *reinterpret_cast<const float4*>(&x[(size_t)(r0 + row) * DD + kc * 4]);
        *reinterpret_cast<float4*>(&xs[row][kc * 4]) = v;
    }
    __syncthreads();

    const int row0 = (t >> 5) * 2;
    const int c0   = (t & 31) * 4;

    const float4 b4 = *reinterpret_cast<const float4*>(&bias[cb + c0]);
    float acc[2][4];
    #pragma unroll
    for (int r = 0; r < 2; ++r) { acc[r][0]=b4.x; acc[r][1]=b4.y; acc[r][2]=b4.z; acc[r][3]=b4.w; }

    for (int kt = 0; kt < DD; kt += 4) {
        const float4 a0 = *reinterpret_cast<const float4*>(&xs[row0][kt]);
        const float4 a1 = *reinterpret_cast<const float4*>(&xs[row0 + 1][kt]);
        const float xa0[4] = {a0.x, a0.y, a0.z, a0.w};
        const float xa1[4] = {a1.x, a1.y, a1.z, a1.w};
        #pragma unroll
        for (int kk = 0; kk < 4; ++kk) {
            const float4 w4 = *reinterpret_cast<const float4*>(&w[(size_t)(kt + kk) * DD + cb + c0]);
            const float wv4[4] = {w4.x, w4.y, w4.z, w4.w};
            #pragma unroll
            for (int c = 0; c < 4; ++c) {
                acc[0][c] = fmaf(xa0[kk], wv4[c], acc[0][c]);
                acc[1][c] = fmaf(xa1[kk], wv4[c], acc[1][c]);
            }
        }
    }
    if (m == 0) {                                 // transposed scatter store
        #pragma unroll
        for (int r = 0; r < 2; ++r) {
            const int rg = r0 + row0 + r;
            const int bb = rg >> 9, j = rg & 511;
            #pragma unroll
            for (int c = 0; c < 4; ++c) {
                const int col = cb + c0 + c;
                const int hh = col >> 6, f = col & 63;
                out[(((size_t)(bb * NH) + hh) * HDIM + f) * NN + j] = acc[r][c];
            }
        }
    } else {
        #pragma unroll
        for (int r = 0; r < 2; ++r) {
            float4 o; o.x = acc[r][0]; o.y = acc[r][1]; o.z = acc[r][2]; o.w = acc[r][3];
            *reinterpret_cast<float4*>(&out[(size_t)(r0 + row0 + r) * DD + cb + c0]) = o;
        }
    }
}

// ------ attn: block = (b, 8 i-rows, one head), 512 threads, 8 waves --------
__global__ __launch_bounds__(512, 4) void attn_kernel(
    const float* __restrict__ hqt, const float* __restrict__ hk, const float* __restrict__ hv,
    const float* __restrict__ a, float* __restrict__ out_hp, float* __restrict__ out_e)
{
    const int t    = threadIdx.x;
    // XCD swizzle: h-blocks of one (b,i-tile) are 128 apart (≡ mod 8 -> same XCD)
    const int h    = blockIdx.x >> 7;
    const int rest = blockIdx.x & 127;
    const int b    = rest >> 6;
    const int i0   = (rest & 63) * 8;

    __shared__ float s[8][NN + 8];                // [ii][j]  16.6 KB
    __shared__ float part[8][8][HDIM];            // [w][ii][col] 16 KB

    const float* hk0 = hk + ((size_t)(b * NN) + i0) * DD + h * HDIM;  // uniform

    // ---- Phase 1: thread = one j; f-major hqT -> lane-consecutive loads;
    // each q scalar serves 8 i-rows; hk via SGPR (uniform) loads.
    {
        const int j = t;
        const float* hqb = hqt + (size_t)(b * NH + h) * HDIM * NN;
        f32x2 accu = {0.f, 0.f};
        f32x2 acc[8] = {};
        #pragma unroll
        for (int fc = 0; fc < 16; ++fc) {
            const int fo = fc * 4;
            const float q0 = hqb[(size_t)(fo + 0) * NN + j];
            const float q1 = hqb[(size_t)(fo + 1) * NN + j];
            const float q2 = hqb[(size_t)(fo + 2) * NN + j];
            const float q3 = hqb[(size_t)(fo + 3) * NN + j];
            const float4 a4 = *reinterpret_cast<const float4*>(a + fo);        // uniform
            const f32x2 av[2] = {{a4.x, a4.y}, {a4.z, a4.w}};
            const f32x2 qv[2] = {{q0, q1}, {q2, q3}};
            #pragma unroll
            for (int ii = 0; ii < 8; ++ii) {
                const float4 kv = *reinterpret_cast<const float4*>(hk0 + ii * DD + fo); // uniform
                const f32x2 kk0 = {kv.x, kv.y}, kk1 = {kv.z, kv.w};
                acc[ii] = pk_fma(pk_abs(qv[0] + kk0), av[0], acc[ii]);
                acc[ii] = pk_fma(pk_abs(qv[1] + kk1), av[1], acc[ii]);
            }
            accu = pk_fma(qv[0], av[0], accu);
            accu = pk_fma(qv[1], av[1], accu);
        }
        const float su = 0.6f * (accu.x + accu.y);
        #pragma unroll
        for (int ii = 0; ii < 8; ++ii)
            s[ii][j] = fmaf(0.4f, acc[ii].x + acc[ii].y, su);
    }
    __syncthreads();

    // ---- Phase 2: softmax over j; 8 waves x 8 rows -> 1 row/wave.
    {
        const int wv = t >> 6, lane = t & 63;
        float* row = &s[wv][0];
        float vals[8]; float mx = -1e30f;
        #pragma unroll
        for (int k2 = 0; k2 < 8; ++k2) { vals[k2] = row[lane + 64 * k2]; mx = fmaxf(mx, vals[k2]); }
        #pragma unroll
        for (int off = 32; off; off >>= 1) mx = fmaxf(mx, __shfl_xor(mx, off, 64));
        float sum = 0.f;
        #pragma unroll
        for (int k2 = 0; k2 < 8; ++k2) { vals[k2] = __expf(vals[k2] - mx); sum += vals[k2]; }
        #pragma unroll
        for (int off = 32; off; off >>= 1) sum += __shfl_xor(sum, off, 64);
        const float inv = 1.0f / sum;
        #pragma unroll
        for (int k2 = 0; k2 < 8; ++k2) row[lane + 64 * k2] = vals[k2] * inv;
    }
    __syncthreads();

    // ---- e-write: out_e[b,i0+ii,j,h], stride-NH scalar stores (merge in L2
    // with the sibling h-blocks on the same XCD).
    {
        float* oe = out_e + (((size_t)(b * NN) + i0) * NN) * NH + h;
        #pragma unroll
        for (int k2 = 0; k2 < 8; ++k2) {
            const int idx = t + 512 * k2;         // 0..4095 = ii*512 + j
            const int ii = idx >> 9;
            const int j  = idx & 511;
            oe[((size_t)ii * NN + j) * NH] = s[ii][j];
        }
    }

    // ---- Phase 3: wave w owns j in [64w,64w+64); lane = (jsub, 4 cols).
    // Row-major float4 hv loads (each serves 8 i-rows); e via LDS broadcast;
    // jsub reduced in-wave via shfl_xor butterfly.
    {
        const int w    = t >> 6;
        const int lane = t & 63;
        const int jsub = lane >> 4;               // 0..3
        const int c0   = (lane & 15) * 4;         // col quad in h-slice
        const int jbase = w * 64;
        f32x2 acc0[8], acc1[8];
        #pragma unroll
        for (int ii = 0; ii < 8; ++ii) { acc0[ii] = f32x2{0.f, 0.f}; acc1[ii] = f32x2{0.f, 0.f}; }
        const float* hvb = hv + (size_t)(b * NN) * DD + h * HDIM + c0;
        #pragma unroll
        for (int it = 0; it < 16; ++it) {
            const int j = jbase + it * 4 + jsub;
            const float4 v4 = *reinterpret_cast<const float4*>(hvb + (size_t)j * DD);
            const f32x2 v0 = {v4.x, v4.y}, v1 = {v4.z, v4.w};
            #pragma unroll
            for (int ii = 0; ii < 8; ++ii) {
                const float e = s[ii][j];          // LDS broadcast (16 lanes/addr)
                const f32x2 e2 = {e, e};
                acc0[ii] = pk_fma(e2, v0, acc0[ii]);
                acc1[ii] = pk_fma(e2, v1, acc1[ii]);
            }
        }
        // reduce over jsub (lane bits 4,5) in-register
        #pragma unroll
        for (int ii = 0; ii < 8; ++ii) {
            #pragma unroll
            for (int off = 16; off <= 32; off <<= 1) {
                acc0[ii].x += __shfl_xor(acc0[ii].x, off, 64);
                acc0[ii].y += __shfl_xor(acc0[ii].y, off, 64);
                acc1[ii].x += __shfl_xor(acc1[ii].x, off, 64);
                acc1[ii].y += __shfl_xor(acc1[ii].y, off, 64);
            }
        }
        if (lane < 16) {
            #pragma unroll
            for (int ii = 0; ii < 8; ++ii) {
                float4 o; o.x = acc0[ii].x; o.y = acc0[ii].y; o.z = acc1[ii].x; o.w = acc1[ii].y;
                *reinterpret_cast<float4*>(&part[w][ii][c0]) = o;
            }
        }
    }
    __syncthreads();
    {
        const int ii = t >> 6, col = t & 63;      // 512 outputs
        float v = 0.f;
        #pragma unroll
        for (int w = 0; w < 8; ++w) v += part[w][ii][col];
        out_hp[((size_t)(b * NN) + i0 + ii) * DD + h * HDIM + col] = v > 0.f ? v : 0.f;
    }
}

extern "C" void kernel_launch(void* const* d_in, const int* in_sizes, int n_in,
                              void* d_out, int out_size, void* d_ws, size_t ws_size,
                              hipStream_t stream) {
    const float* q   = (const float*)d_in[0];
    const float* kin = (const float*)d_in[1];
    const float* vin = (const float*)d_in[2];
    const float* wq  = (const float*)d_in[3];
    const float* bq  = (const float*)d_in[4];
    const float* wv  = (const float*)d_in[5];
    const float* bv  = (const float*)d_in[6];
    const float* a   = (const float*)d_in[7];

    float* out_hp = (float*)d_out;                    // [B,N,256]
    float* out_e  = out_hp + (size_t)NB * NN * DD;    // [B,N,N,4]

    float* hqt = (float*)d_ws;                        // hqT[b][h][f][j], 1 MB
    float* hk  = hqt + (size_t)NB * NN * DD;
    float* hv  = hk  + (size_t)NB * NN * DD;

    proj_kernel<<<dim3(64, 2, 3), 256, 0, stream>>>(q, kin, vin, wq, bq, wv, bv, hqt, hk, hv);
    attn_kernel<<<dim3(NB * 64 * NH), 512, 0, stream>>>(hqt, hk, hv, a, out_hp, out_e);
}